// Round 6
// baseline (188.978 us; speedup 1.0000x reference)
//
#include <hip/hip_runtime.h>
#include <math.h>

// EKF propagate: B=65536, nx=16, nz=8, nu=4, fp32.
//
// R10 = persistent grid-stride R6. Evidence across R4-R9: per-resident-wave
// VALU issue share is invariant (~20-25%) across ALL structures; VALUBusy =
// k * resident-waves. Measured residency never exceeds ~11-13 waves/CU even
// with static caps of 24-32 (R4/R5), and every structural edit that reduced
// waves (R6/R7/R9) lost utilization proportionally. Hypothesis: short-lived
// (~13us) near-lockstep blocks retire in convoys and CUs sit part-empty
// during refill; static-occupancy reasoning never sees this.
// R10: 1024 blocks (exactly 4/CU = LDS static cap) x 256 thr, each block
// grid-strides over 2 element-sets. Blocks never retire mid-kernel ->
// residency pinned at 16 waves/CU; cross-iteration ILP (iter-2 Sigma loads
// overlap iter-1 epilogue) comes free. Per-element code is UNCHANGED R6.
// Cross-iteration LDS reuse is safe: all hazards are within-wave DS
// ordering (in-order), wave_barrier pins compiler order.

namespace {

constexpr int LPE    = 8;            // lanes per element
constexpr int GROUPS = 32;           // elements per block-iteration
constexpr int TPB    = GROUPS * LPE; // 256 threads
constexpr int NBLK   = 1024;         // persistent blocks = 4/CU (LDS cap)

// Per-group LDS layout (floats). Overlays by liveness:
//  [0,256)   VT : V^T 16x16                           [V .. W]
//  [0,128)   TPT: tp^T, 8 rows x 16  (overlay)        [tp .. final]
//  [128,192) SI : S^-1 rows 8x8                       [post-GJ .. K]
//  [256,272) mubar[16]; [272,288) d[16]; [288,296) h[8]; [296,304) dh[8]
constexpr int O_VT  = 0;
constexpr int O_TPT = 0;
constexpr int O_SI  = 128;
constexpr int O_MU  = 256;
constexpr int O_D   = 272;
constexpr int O_H   = 288;
constexpr int O_DH  = 296;
constexpr int GS    = 308;  // %32==20, %4==0

__device__ __forceinline__ float dot4(float4 a, float4 b) {
  return a.x*b.x + a.y*b.y + a.z*b.z + a.w*b.w;
}

// tanh(x) = 1 - 2/(e^{2x}+1); v_exp_f32 + v_rcp_f32. abs err ~1e-7.
__device__ __forceinline__ float tanh_fast(float x) {
  float e = __expf(2.0f * x);
  return 1.0f - 2.0f * __builtin_amdgcn_rcpf(e + 1.0f);
}

// ds_swizzle BitMode: src_lane = ((lane & 0x18) | P) -> broadcast lane P of
// each 8-lane group (offset imm must be a literal -> macro, not function).
#define SWZF(v, imm) __int_as_float(__builtin_amdgcn_ds_swizzle(__float_as_int(v), (imm)))

// One Gauss-Jordan elimination step for pivot P (P is a literal).
// Rows live in registers: s8[8] (S row t), x8[8] (inverse row t).
// Invariants at entry to step P:
//   - s8[j] maintained for j >= P;  x8[j] maintained for j < P; x8[j>=P]=delta_tj
//   - pivot row's x8[P] == 1 (so px[P]*rp == rp, no swizzle needed)
// f-trick: for t==P, f = ps[P]-1 makes  s8[j] - f*(ps[j]*rp) == ps[j]*rp
// (the normalized pivot row) -- branchless unification, 1 cndmask per step.
#define GJ_STEP(P)                                                         \
  {                                                                        \
    float ps[8], px[8];                                                    \
    _Pragma("unroll")                                                      \
    for (int j = 0; j < 8; j++) {                                          \
      if (j >= (P)) ps[j] = SWZF(s8[j], (((P) << 5) | 0x18));              \
      else          px[j] = SWZF(x8[j], (((P) << 5) | 0x18));              \
    }                                                                      \
    const float rp = __builtin_amdgcn_rcpf(ps[(P)]);                       \
    const float f  = (t == (P)) ? (ps[(P)] - 1.0f) : s8[(P)];              \
    _Pragma("unroll")                                                      \
    for (int j = 0; j < 8; j++) {                                          \
      if (j > (P))      s8[j] -= f * (ps[j] * rp);                         \
      else if (j < (P)) x8[j] -= f * (px[j] * rp);                         \
    }                                                                      \
    x8[(P)] -= f * rp;                                                     \
  }

__global__ __launch_bounds__(TPB)
void ekf_kernel(const float* __restrict__ mu_prev,
                const float* __restrict__ Sig_prev,
                const float* __restrict__ U,
                const float* __restrict__ Z,
                const float* __restrict__ A,
                const float* __restrict__ Bm,
                const float* __restrict__ C,
                const float* __restrict__ Q,
                const float* __restrict__ R,
                float* __restrict__ mu_out,
                float* __restrict__ sig_out,
                int Btot)
{
  __shared__ float lds[GS * GROUPS];   // 39424 B -> 4 blocks/CU
  const int tid = threadIdx.x;
  const int g = tid >> 3;              // group (element) within block
  const int t = tid & 7;               // lane within group
  float* L = lds + g * GS;
  const int r0 = t, r1 = t + 8;        // owned matrix rows

  // Persistent grid-stride loop: blocks never retire mid-kernel.
  for (int e = blockIdx.x * GROUPS + g; e < Btot; e += NBLK * GROUPS) {

  // ---- load Sigma rows r0, r1 ----
  float sig0[16], sig1[16];
  {
    const float4* s0 = (const float4*)(Sig_prev + (size_t)e * 256 + r0 * 16);
    const float4* s1 = (const float4*)(Sig_prev + (size_t)e * 256 + r1 * 16);
    #pragma unroll
    for (int c = 0; c < 4; c++) {
      float4 v0 = s0[c], v1 = s1[c];
      sig0[4*c+0]=v0.x; sig0[4*c+1]=v0.y; sig0[4*c+2]=v0.z; sig0[4*c+3]=v0.w;
      sig1[4*c+0]=v1.x; sig1[4*c+1]=v1.y; sig1[4*c+2]=v1.z; sig1[4*c+3]=v1.w;
    }
  }

  // ---- mu_bar rows r0,r1 (dual independent chains) ----
  float mubar0, mubar1, d0loc, d1loc;
  {
    const float4* mr = (const float4*)(mu_prev + (size_t)e * 16);
    float4 m0 = mr[0], m1 = mr[1], m2 = mr[2], m3 = mr[3];
    const float4* a0 = (const float4*)(A + r0 * 16);
    const float4* a1 = (const float4*)(A + r1 * 16);
    float p0 = dot4(a0[0],m0)+dot4(a0[1],m1)+dot4(a0[2],m2)+dot4(a0[3],m3);
    float p1 = dot4(a1[0],m0)+dot4(a1[1],m1)+dot4(a1[2],m2)+dot4(a1[3],m3);
    float4 u4 = *(const float4*)(U + (size_t)e * 4);
    p0 += dot4(*(const float4*)(Bm + r0 * 4), u4);
    p1 += dot4(*(const float4*)(Bm + r1 * 4), u4);
    mubar0 = tanh_fast(p0); d0loc = 1.0f - mubar0 * mubar0;
    mubar1 = tanh_fast(p1); d1loc = 1.0f - mubar1 * mubar1;
  }
  L[O_MU + r0] = mubar0; L[O_MU + r1] = mubar1;
  L[O_D  + r0] = d0loc;  L[O_D  + r1] = d1loc;
  __builtin_amdgcn_wave_barrier();

  // ---- h[t], dh[t]; keep C row t in regs for S-build ----
  float4 ct0, ct1, ct2, ct3;
  float dhl;
  {
    const float4* cr = (const float4*)(C + t * 16);
    ct0 = cr[0]; ct1 = cr[1]; ct2 = cr[2]; ct3 = cr[3];
    const float4* mb = (const float4*)(L + O_MU);
    float ph = dot4(ct0,mb[0])+dot4(ct1,mb[1])+dot4(ct2,mb[2])+dot4(ct3,mb[3]);
    float hb = tanh_fast(ph); dhl = 1.0f - hb * hb;
    L[O_H + t] = hb; L[O_DH + t] = dhl;
  }
  __builtin_amdgcn_wave_barrier();
  float dh[8];
  {
    float4 v0 = *(const float4*)(L + O_DH);
    float4 v1 = *(const float4*)(L + O_DH + 4);
    dh[0]=v0.x; dh[1]=v0.y; dh[2]=v0.z; dh[3]=v0.w;
    dh[4]=v1.x; dh[5]=v1.y; dh[6]=v1.z; dh[7]=v1.w;
  }

  // ---- V = Sig * A^T rows r0,r1; scatter V^T (2 FMA per uniform s_load) ----
  #pragma unroll
  for (int j = 0; j < 16; j++) {
    float acc0 = 0.f, acc1 = 0.f;
    #pragma unroll
    for (int k = 0; k < 16; k++) {
      float a = A[j*16 + k];                  // uniform -> s_load
      acc0 += sig0[k] * a; acc1 += sig1[k] * a;
    }
    L[O_VT + j*16 + r0] = acc0;               // b32 writes: 2-way max
    L[O_VT + j*16 + r1] = acc1;
  }
  __builtin_amdgcn_wave_barrier();

  // ---- W rows r0,r1 (W = A*V, symmetric: col c == row c) ----
  float sb0[16], sb1[16];
  {
    float v0[16], v1[16];
    const float4* p0 = (const float4*)(L + O_VT + r0 * 16);
    const float4* p1 = (const float4*)(L + O_VT + r1 * 16);
    #pragma unroll
    for (int c = 0; c < 4; c++) {
      float4 x0 = p0[c], x1 = p1[c];
      v0[4*c+0]=x0.x; v0[4*c+1]=x0.y; v0[4*c+2]=x0.z; v0[4*c+3]=x0.w;
      v1[4*c+0]=x1.x; v1[4*c+1]=x1.y; v1[4*c+2]=x1.z; v1[4*c+3]=x1.w;
    }
    #pragma unroll
    for (int i = 0; i < 16; i++) {
      float acc0 = 0.f, acc1 = 0.f;
      #pragma unroll
      for (int k = 0; k < 16; k++) {
        float a = A[i*16 + k];                // uniform -> s_load
        acc0 += a * v0[k]; acc1 += a * v1[k];
      }
      sb0[i] = acc0; sb1[i] = acc1;
    }
  }
  __builtin_amdgcn_wave_barrier();            // VT dead; TPT may overlay

  // ---- Sig_bar rows: sb_r = R[r,:] + d_r * W[r,:] * d ----
  {
    const float4* rr0 = (const float4*)(R + r0 * 16);
    const float4* rr1 = (const float4*)(R + r1 * 16);
    const float4* dv  = (const float4*)(L + O_D);
    #pragma unroll
    for (int c = 0; c < 4; c++) {
      float4 ra = rr0[c], rb = rr1[c], dd = dv[c];
      sb0[4*c+0] = ra.x + d0loc*sb0[4*c+0]*dd.x;
      sb0[4*c+1] = ra.y + d0loc*sb0[4*c+1]*dd.y;
      sb0[4*c+2] = ra.z + d0loc*sb0[4*c+2]*dd.z;
      sb0[4*c+3] = ra.w + d0loc*sb0[4*c+3]*dd.w;
      sb1[4*c+0] = rb.x + d1loc*sb1[4*c+0]*dd.x;
      sb1[4*c+1] = rb.y + d1loc*sb1[4*c+1]*dd.y;
      sb1[4*c+2] = rb.z + d1loc*sb1[4*c+2]*dd.z;
      sb1[4*c+3] = rb.w + d1loc*sb1[4*c+3]*dd.w;
    }
  }

  // ---- tp rows r0,r1 = Sig_bar[r,:] C^T Dh ; scatter tp^T ----
  float tp0[8], tp1[8];
  #pragma unroll
  for (int m = 0; m < 8; m++) {
    float acc0 = 0.f, acc1 = 0.f;
    #pragma unroll
    for (int k = 0; k < 16; k++) {
      float c = C[m*16 + k];                  // uniform -> s_load
      acc0 += sb0[k] * c; acc1 += sb1[k] * c;
    }
    tp0[m] = acc0 * dh[m]; tp1[m] = acc1 * dh[m];
    L[O_TPT + m*16 + r0] = tp0[m];
    L[O_TPT + m*16 + r1] = tp1[m];
  }
  __builtin_amdgcn_wave_barrier();

  // ---- S row t = dh_t * (C[t,:] @ tp) + Q[t,:]  (all 8 lanes active) ----
  float s8[8];
  {
    float4 q0 = *(const float4*)(Q + t * 8);
    float4 q1 = *(const float4*)(Q + t * 8 + 4);
    float qv[8] = {q0.x,q0.y,q0.z,q0.w,q1.x,q1.y,q1.z,q1.w};
    #pragma unroll
    for (int m = 0; m < 8; m++) {
      const float4* tr = (const float4*)(L + O_TPT + m * 16);  // broadcast
      float acc = dot4(ct0,tr[0]) + dot4(ct1,tr[1])
                + dot4(ct2,tr[2]) + dot4(ct3,tr[3]);
      s8[m] = acc * dhl + qv[m];
    }
  }

  // ---- Gauss-Jordan inverse of S via swizzle broadcasts (no LDS, no
  //      barriers, all lanes active; S SPD -> no pivoting) ----
  float x8[8];
  #pragma unroll
  for (int j = 0; j < 8; j++) x8[j] = (j == t) ? 1.0f : 0.0f;
  GJ_STEP(0) GJ_STEP(1) GJ_STEP(2) GJ_STEP(3)
  GJ_STEP(4) GJ_STEP(5) GJ_STEP(6) GJ_STEP(7)

  // ---- stash S^-1 rows ----
  *((float4*)(L + O_SI + t*8 + 0)) = make_float4(x8[0], x8[1], x8[2], x8[3]);
  *((float4*)(L + O_SI + t*8 + 4)) = make_float4(x8[4], x8[5], x8[6], x8[7]);
  __builtin_amdgcn_wave_barrier();

  // ---- K rows r0,r1 = tp[r,:] @ Sinv ----
  float k0[8] = {0,0,0,0,0,0,0,0};
  float k1[8] = {0,0,0,0,0,0,0,0};
  #pragma unroll
  for (int m = 0; m < 8; m++) {
    float4 a = *(const float4*)(L + O_SI + m*8 + 0);   // broadcast
    float4 b = *(const float4*)(L + O_SI + m*8 + 4);
    float f0 = tp0[m], f1 = tp1[m];
    k0[0]+=f0*a.x; k0[1]+=f0*a.y; k0[2]+=f0*a.z; k0[3]+=f0*a.w;
    k0[4]+=f0*b.x; k0[5]+=f0*b.y; k0[6]+=f0*b.z; k0[7]+=f0*b.w;
    k1[0]+=f1*a.x; k1[1]+=f1*a.y; k1[2]+=f1*a.z; k1[3]+=f1*a.w;
    k1[4]+=f1*b.x; k1[5]+=f1*b.y; k1[6]+=f1*b.z; k1[7]+=f1*b.w;
  }

  // ---- mu rows r0,r1 ----
  {
    float4 z0 = *(const float4*)(Z + (size_t)e * 8);
    float4 z1 = *(const float4*)(Z + (size_t)e * 8 + 4);
    float4 h0 = *(const float4*)(L + O_H);
    float4 h1 = *(const float4*)(L + O_H + 4);
    float i0=z0.x-h0.x, i1=z0.y-h0.y, i2=z0.z-h0.z, i3=z0.w-h0.w;
    float i4=z1.x-h1.x, i5=z1.y-h1.y, i6=z1.z-h1.z, i7=z1.w-h1.w;
    float mu0 = mubar0 + k0[0]*i0+k0[1]*i1+k0[2]*i2+k0[3]*i3
                       + k0[4]*i4+k0[5]*i5+k0[6]*i6+k0[7]*i7;
    float mu1 = mubar1 + k1[0]*i0+k1[1]*i1+k1[2]*i2+k1[3]*i3
                       + k1[4]*i4+k1[5]*i5+k1[6]*i6+k1[7]*i7;
    mu_out[(size_t)e * 16 + r0] = mu0;
    mu_out[(size_t)e * 16 + r1] = mu1;
  }

  // ---- Sig_now rows = Sig_bar - K tp^T  (K S = tp exactly in real
  //      arithmetic -> equals Joseph form; fp delta ~1e-6) ----
  #pragma unroll
  for (int m = 0; m < 8; m++) {
    const float4* tr = (const float4*)(L + O_TPT + m * 16);  // broadcast
    float4 t0 = tr[0], t1 = tr[1], t2 = tr[2], t3 = tr[3];
    float km0 = k0[m], km1 = k1[m];
    sb0[0] -=km0*t0.x; sb0[1] -=km0*t0.y; sb0[2] -=km0*t0.z; sb0[3] -=km0*t0.w;
    sb0[4] -=km0*t1.x; sb0[5] -=km0*t1.y; sb0[6] -=km0*t1.z; sb0[7] -=km0*t1.w;
    sb0[8] -=km0*t2.x; sb0[9] -=km0*t2.y; sb0[10]-=km0*t2.z; sb0[11]-=km0*t2.w;
    sb0[12]-=km0*t3.x; sb0[13]-=km0*t3.y; sb0[14]-=km0*t3.z; sb0[15]-=km0*t3.w;
    sb1[0] -=km1*t0.x; sb1[1] -=km1*t0.y; sb1[2] -=km1*t0.z; sb1[3] -=km1*t0.w;
    sb1[4] -=km1*t1.x; sb1[5] -=km1*t1.y; sb1[6] -=km1*t1.z; sb1[7] -=km1*t1.w;
    sb1[8] -=km1*t2.x; sb1[9] -=km1*t2.y; sb1[10]-=km1*t2.z; sb1[11]-=km1*t2.w;
    sb1[12]-=km1*t3.x; sb1[13]-=km1*t3.y; sb1[14]-=km1*t3.z; sb1[15]-=km1*t3.w;
  }
  {
    float4* o0 = (float4*)(sig_out + (size_t)e * 256 + r0 * 16);
    float4* o1 = (float4*)(sig_out + (size_t)e * 256 + r1 * 16);
    o0[0] = make_float4(sb0[0],  sb0[1],  sb0[2],  sb0[3]);
    o0[1] = make_float4(sb0[4],  sb0[5],  sb0[6],  sb0[7]);
    o0[2] = make_float4(sb0[8],  sb0[9],  sb0[10], sb0[11]);
    o0[3] = make_float4(sb0[12], sb0[13], sb0[14], sb0[15]);
    o1[0] = make_float4(sb1[0],  sb1[1],  sb1[2],  sb1[3]);
    o1[1] = make_float4(sb1[4],  sb1[5],  sb1[6],  sb1[7]);
    o1[2] = make_float4(sb1[8],  sb1[9],  sb1[10], sb1[11]);
    o1[3] = make_float4(sb1[12], sb1[13], sb1[14], sb1[15]);
  }

  // One more barrier before the next iteration overwrites MU/D/H/DH and VT
  // (safe by in-wave DS ordering; this pins the compiler's order).
  __builtin_amdgcn_wave_barrier();
  }  // grid-stride loop
}

} // namespace

extern "C" void kernel_launch(void* const* d_in, const int* in_sizes, int n_in,
                              void* d_out, int out_size, void* d_ws, size_t ws_size,
                              hipStream_t stream)
{
  const float* mu_prev = (const float*)d_in[0];
  const float* Sigma   = (const float*)d_in[1];
  const float* u       = (const float*)d_in[2];
  const float* z       = (const float*)d_in[3];
  const float* A       = (const float*)d_in[4];
  const float* Bm      = (const float*)d_in[5];
  const float* C       = (const float*)d_in[6];
  const float* Q       = (const float*)d_in[7];
  const float* R       = (const float*)d_in[8];

  const int Btot = in_sizes[0] / 16;                 // B = 65536
  float* mu_out  = (float*)d_out;
  float* sig_out = (float*)d_out + (size_t)Btot * 16;

  int grid = (Btot + GROUPS - 1) / GROUPS;           // sets needed
  if (grid > NBLK) grid = NBLK;                      // 1024 persistent blocks
  ekf_kernel<<<grid, TPB, 0, stream>>>(mu_prev, Sigma, u, z, A, Bm, C, Q, R,
                                       mu_out, sig_out, Btot);
}

// Round 7
// 160.729 us; speedup vs baseline: 1.1758x; 1.1758x over previous
//
#include <hip/hip_runtime.h>
#include <math.h>

// EKF propagate: B=65536, nx=16, nz=8, nu=4, fp32.
//
// R11 = R4's occupancy envelope (16 lanes/elt, TPB 256, LDS 27136 -> 6
// blocks/CU, the best-measured wave-fill: 12.9 waves/CU, VALUBusy 62%)
// with every independently-proven join/work cut folded in:
//  1. Gauss-Jordan via ds_swizzle broadcasts (R6-proven), REPLICATED on
//     both 8-lane halves of the 16-lane group: no divergence, no LDS
//     round trips (R4 had 16 write->barrier->read joins, half-wave idle).
//  2. Full-wave S-build using S symmetry: lane t computes S column t&7
//     (== row t&7), C rows stream uniformly via s_load (R4 masked t<8).
//  3. Phase-separated V: all 16 dot products into registers first, then a
//     burst of 16 ds_writes -> no SMEM<->DS interleave inside the loop
//     (SMEM completes out-of-order and shares lgkmcnt with DS; mixing
//     forces full-drain waits).
//  4. tanh_fast (exp+rcp, R5-proven), no TPB copy, no PIV buffer.
// Per-wave lgkm joins ~45 -> ~7; VALU cycles/wave ~5.9k -> ~5.1k.
// v_pk_fma_f32 deliberately NOT used: gfx950 fp32 peak (157.3 TF) is
// unpacked lane-rate; packed math saves issue slots, not VALU cycles.

namespace {

constexpr int GROUPS = 16;            // elements per block
constexpr int TPB    = GROUPS * 16;   // 256 threads
constexpr int GS     = 424;           // floats/group; 424*16*4 = 27136 B
                                      // -> 6 blocks/CU (R4 envelope).
                                      // 424%32==8: wave's 4 groups at bank
                                      // offsets {0,8,16,24}; %4==0 aligned.

// Per-group LDS layout (floats). Overlays by liveness:
//  [0,256)   VT : V^T 16x16 stride 16            [V .. W]
//  [0,128)   TPT: tp^T 8x16      (overlay)       [tp .. final]
//  [128,192) SI : S^-1 rows 8x8  (overlay VT hi) [post-GJ .. K]
//  [256,272) mubar[16]; [272,288) d[16]; [288,296) h[8]; [296,304) dh[8]
constexpr int O_VT  = 0;
constexpr int O_TPT = 0;
constexpr int O_SI  = 128;
constexpr int O_MU  = 256;
constexpr int O_D   = 272;
constexpr int O_H   = 288;
constexpr int O_DH  = 296;

__device__ __forceinline__ float dot4(float4 a, float4 b) {
  return a.x*b.x + a.y*b.y + a.z*b.z + a.w*b.w;
}

// tanh(x) = 1 - 2/(e^{2x}+1); v_exp_f32 + v_rcp_f32. abs err ~1e-7.
__device__ __forceinline__ float tanh_fast(float x) {
  float e = __expf(2.0f * x);
  return 1.0f - 2.0f * __builtin_amdgcn_rcpf(e + 1.0f);
}

// ds_swizzle BitMode: src = (lane & 0x18) | P -> broadcast lane P within
// each aligned 8-lane subgroup (imm must be a literal -> macro).
#define SWZF(v, imm) __int_as_float(__builtin_amdgcn_ds_swizzle(__float_as_int(v), (imm)))

// One Gauss-Jordan step for pivot P (literal). Rows in registers:
// s8[8] (S row tl), x8[8] (inverse row tl), tl = t&7; both 8-lane halves
// of the 16-lane group run identical copies (replication, no divergence).
// Invariants at entry to step P:
//   s8[j] maintained for j>=P; x8[j] maintained for j<P; x8[j>=P]=delta;
//   pivot row's x8[P]==1. f-trick: for tl==P, f=ps[P]-1 makes
//   s8[j]-f*(ps[j]*rp) == ps[j]*rp (normalized pivot row) -- branchless.
#define GJ_STEP(P)                                                         \
  {                                                                        \
    float ps[8], px[8];                                                    \
    _Pragma("unroll")                                                      \
    for (int j = 0; j < 8; j++) {                                          \
      if (j >= (P)) ps[j] = SWZF(s8[j], (((P) << 5) | 0x18));              \
      else          px[j] = SWZF(x8[j], (((P) << 5) | 0x18));              \
    }                                                                      \
    const float rp = __builtin_amdgcn_rcpf(ps[(P)]);                       \
    const float f  = (tl == (P)) ? (ps[(P)] - 1.0f) : s8[(P)];             \
    _Pragma("unroll")                                                      \
    for (int j = 0; j < 8; j++) {                                          \
      if (j > (P))      s8[j] -= f * (ps[j] * rp);                         \
      else if (j < (P)) x8[j] -= f * (px[j] * rp);                         \
    }                                                                      \
    x8[(P)] -= f * rp;                                                     \
  }

__global__ __launch_bounds__(TPB)     // no min-waves clause (R3 lesson)
void ekf_kernel(const float* __restrict__ mu_prev,
                const float* __restrict__ Sig_prev,
                const float* __restrict__ U,
                const float* __restrict__ Z,
                const float* __restrict__ A,
                const float* __restrict__ Bm,
                const float* __restrict__ C,
                const float* __restrict__ Q,
                const float* __restrict__ R,
                float* __restrict__ mu_out,
                float* __restrict__ sig_out,
                int Btot)
{
  __shared__ float lds[GS * GROUPS];   // 27136 B -> 6 blocks/CU
  const int tid = threadIdx.x;
  const int g  = tid >> 4;
  const int t  = tid & 15;
  const int tl = t & 7;
  int e = blockIdx.x * GROUPS + g;
  if (e >= Btot) e = Btot - 1;         // clamp; duplicate-write benign
  float* L = lds + g * GS;

  // ---- load Sigma row t (coalesced: group covers contiguous 1KB) ----
  float sig[16];
  {
    const float4* sp = (const float4*)(Sig_prev + (size_t)e * 256 + t * 16);
    #pragma unroll
    for (int c = 0; c < 4; c++) {
      float4 v = sp[c];
      sig[4*c+0] = v.x; sig[4*c+1] = v.y; sig[4*c+2] = v.z; sig[4*c+3] = v.w;
    }
  }

  // ---- mu_bar_t = tanh(A[t,:].mu + Bm[t,:].u), d_t ----
  float mubar, dloc;
  {
    const float4* ar = (const float4*)(A + t * 16);      // per-lane row, L1
    const float4* mr = (const float4*)(mu_prev + (size_t)e * 16);
    float pre = dot4(ar[0], mr[0]) + dot4(ar[1], mr[1])
              + dot4(ar[2], mr[2]) + dot4(ar[3], mr[3]);
    float4 b4 = *(const float4*)(Bm + t * 4);
    float4 u4 = *(const float4*)(U + (size_t)e * 4);
    pre += dot4(b4, u4);
    mubar = tanh_fast(pre);
    dloc  = 1.0f - mubar * mubar;
  }
  L[O_MU + t] = mubar;
  L[O_D  + t] = dloc;
  __builtin_amdgcn_wave_barrier();

  // ---- h_bar, dh on lanes t<8 ----
  if (t < 8) {
    const float4* cr = (const float4*)(C + t * 16);
    const float4* mb = (const float4*)(L + O_MU);
    float ph = dot4(cr[0], mb[0]) + dot4(cr[1], mb[1])
             + dot4(cr[2], mb[2]) + dot4(cr[3], mb[3]);
    float hb = tanh_fast(ph);
    L[O_H  + t] = hb;
    L[O_DH + t] = 1.0f - hb * hb;
  }
  __builtin_amdgcn_wave_barrier();

  float dh[8];
  {
    float4 d0 = *(const float4*)(L + O_DH);
    float4 d1 = *(const float4*)(L + O_DH + 4);
    dh[0]=d0.x; dh[1]=d0.y; dh[2]=d0.z; dh[3]=d0.w;
    dh[4]=d1.x; dh[5]=d1.y; dh[6]=d1.z; dh[7]=d1.w;
  }

  // ---- V = Sig * A^T row t: PHASE-SEPARATED -- all 16 dots into regs
  //      (pure SMEM+VALU), then a burst of 16 ds_writes ----
  float vv[16];
  #pragma unroll
  for (int j = 0; j < 16; j++) {
    float acc = 0.f;
    #pragma unroll
    for (int k = 0; k < 16; k++) acc += sig[k] * A[j*16 + k];  // s_load
    vv[j] = acc;
  }
  #pragma unroll
  for (int j = 0; j < 16; j++) L[O_VT + j*16 + t] = vv[j];     // V^T scatter
  __builtin_amdgcn_wave_barrier();

  // ---- vcol = V[:,t] (contiguous VT row t) ----
  float vcol[16];
  {
    const float4* vt = (const float4*)(L + O_VT + t * 16);
    #pragma unroll
    for (int c = 0; c < 4; c++) {
      float4 v = vt[c];
      vcol[4*c+0]=v.x; vcol[4*c+1]=v.y; vcol[4*c+2]=v.z; vcol[4*c+3]=v.w;
    }
  }

  // ---- W col t == W row t (sym); fuse Sig_bar: sb = R[t,:] + d_t*W*d ----
  float sb[16];
  {
    float rr[16], dv[16];
    const float4* rp4 = (const float4*)(R + t * 16);
    const float4* dp4 = (const float4*)(L + O_D);
    #pragma unroll
    for (int c = 0; c < 4; c++) {
      float4 r4 = rp4[c], d4 = dp4[c];
      rr[4*c+0]=r4.x; rr[4*c+1]=r4.y; rr[4*c+2]=r4.z; rr[4*c+3]=r4.w;
      dv[4*c+0]=d4.x; dv[4*c+1]=d4.y; dv[4*c+2]=d4.z; dv[4*c+3]=d4.w;
    }
    #pragma unroll
    for (int i = 0; i < 16; i++) {
      float acc = 0.f;
      #pragma unroll
      for (int k = 0; k < 16; k++) acc += A[i*16 + k] * vcol[k]; // s_load
      sb[i] = rr[i] + dloc * acc * dv[i];
    }
  }

  // ---- tp row t = Sig_bar[t,:] C^T Dh: regs first, then burst writes ----
  float tpv[8];
  #pragma unroll
  for (int m = 0; m < 8; m++) {
    float acc = 0.f;
    #pragma unroll
    for (int k = 0; k < 16; k++) acc += sb[k] * C[m*16 + k];     // s_load
    tpv[m] = acc * dh[m];
  }
  #pragma unroll
  for (int m = 0; m < 8; m++) L[O_TPT + m*16 + t] = tpv[m];      // tp^T
  __builtin_amdgcn_wave_barrier();

  // ---- S col tl (== row tl, S sym): ALL 16 lanes active (halves dup).
  //      s8[m] = dh[m]*(C[m,:].tp[:,tl]) + Q[m][tl]; C rows via s_load ----
  float s8[8];
  {
    float tc[16];
    const float4* tt = (const float4*)(L + O_TPT + tl * 16);  // tp[:,tl]
    #pragma unroll
    for (int c = 0; c < 4; c++) {
      float4 v = tt[c];
      tc[4*c+0]=v.x; tc[4*c+1]=v.y; tc[4*c+2]=v.z; tc[4*c+3]=v.w;
    }
    float4 q0 = *(const float4*)(Q + tl * 8);     // Q row tl == col tl (sym)
    float4 q1 = *(const float4*)(Q + tl * 8 + 4);
    float qv[8] = {q0.x,q0.y,q0.z,q0.w,q1.x,q1.y,q1.z,q1.w};
    #pragma unroll
    for (int m = 0; m < 8; m++) {
      float acc = 0.f;
      #pragma unroll
      for (int k = 0; k < 16; k++) acc += C[m*16 + k] * tc[k];   // s_load
      s8[m] = acc * dh[m] + qv[m];
    }
  }

  // ---- Gauss-Jordan inverse of S via swizzle broadcasts (no LDS, no
  //      joins, full wave active; S SPD -> no pivoting) ----
  float x8[8];
  #pragma unroll
  for (int j = 0; j < 8; j++) x8[j] = (j == tl) ? 1.0f : 0.0f;
  GJ_STEP(0) GJ_STEP(1) GJ_STEP(2) GJ_STEP(3)
  GJ_STEP(4) GJ_STEP(5) GJ_STEP(6) GJ_STEP(7)

  // ---- stash S^-1 rows (lower half only; both halves identical) ----
  if (t < 8) {
    *((float4*)(L + O_SI + t*8 + 0)) = make_float4(x8[0], x8[1], x8[2], x8[3]);
    *((float4*)(L + O_SI + t*8 + 4)) = make_float4(x8[4], x8[5], x8[6], x8[7]);
  }
  __builtin_amdgcn_wave_barrier();

  // ---- K row t = tp[t,:] @ Sinv ----
  float kreg[8] = {0,0,0,0,0,0,0,0};
  #pragma unroll
  for (int m = 0; m < 8; m++) {
    float4 a = *(const float4*)(L + O_SI + m*8 + 0);   // group broadcast
    float4 b = *(const float4*)(L + O_SI + m*8 + 4);
    float f = tpv[m];
    kreg[0]+=f*a.x; kreg[1]+=f*a.y; kreg[2]+=f*a.z; kreg[3]+=f*a.w;
    kreg[4]+=f*b.x; kreg[5]+=f*b.y; kreg[6]+=f*b.z; kreg[7]+=f*b.w;
  }

  // ---- mu_now_t = mu_bar_t + K[t,:].(z - h_bar) ----
  {
    float4 z0 = *(const float4*)(Z + (size_t)e * 8);
    float4 z1 = *(const float4*)(Z + (size_t)e * 8 + 4);
    float4 h0 = *(const float4*)(L + O_H);
    float4 h1 = *(const float4*)(L + O_H + 4);
    float mu_now = mubar
      + kreg[0]*(z0.x-h0.x) + kreg[1]*(z0.y-h0.y)
      + kreg[2]*(z0.z-h0.z) + kreg[3]*(z0.w-h0.w)
      + kreg[4]*(z1.x-h1.x) + kreg[5]*(z1.y-h1.y)
      + kreg[6]*(z1.z-h1.z) + kreg[7]*(z1.w-h1.w);
    mu_out[(size_t)e * 16 + t] = mu_now;
  }

  // ---- Sig_now row t = Sig_bar - K tp^T (== Joseph form exactly in real
  //      arithmetic, since K S = tp; fp delta ~1e-6) ----
  float out[16];
  #pragma unroll
  for (int i = 0; i < 16; i++) out[i] = sb[i];
  #pragma unroll
  for (int m = 0; m < 8; m++) {
    const float4* tr = (const float4*)(L + O_TPT + m * 16);  // broadcast
    float4 t0 = tr[0], t1 = tr[1], t2 = tr[2], t3 = tr[3];
    float km = kreg[m];
    out[0]  -= km*t0.x; out[1]  -= km*t0.y; out[2]  -= km*t0.z; out[3]  -= km*t0.w;
    out[4]  -= km*t1.x; out[5]  -= km*t1.y; out[6]  -= km*t1.z; out[7]  -= km*t1.w;
    out[8]  -= km*t2.x; out[9]  -= km*t2.y; out[10] -= km*t2.z; out[11] -= km*t2.w;
    out[12] -= km*t3.x; out[13] -= km*t3.y; out[14] -= km*t3.z; out[15] -= km*t3.w;
  }
  {
    float4* op = (float4*)(sig_out + (size_t)e * 256 + t * 16);
    op[0] = make_float4(out[0],  out[1],  out[2],  out[3]);
    op[1] = make_float4(out[4],  out[5],  out[6],  out[7]);
    op[2] = make_float4(out[8],  out[9],  out[10], out[11]);
    op[3] = make_float4(out[12], out[13], out[14], out[15]);
  }
}

} // namespace

extern "C" void kernel_launch(void* const* d_in, const int* in_sizes, int n_in,
                              void* d_out, int out_size, void* d_ws, size_t ws_size,
                              hipStream_t stream)
{
  const float* mu_prev = (const float*)d_in[0];
  const float* Sigma   = (const float*)d_in[1];
  const float* u       = (const float*)d_in[2];
  const float* z       = (const float*)d_in[3];
  const float* A       = (const float*)d_in[4];
  const float* Bm      = (const float*)d_in[5];
  const float* C       = (const float*)d_in[6];
  const float* Q       = (const float*)d_in[7];
  const float* R       = (const float*)d_in[8];

  const int Btot = in_sizes[0] / 16;                 // B = 65536
  float* mu_out  = (float*)d_out;
  float* sig_out = (float*)d_out + (size_t)Btot * 16;

  const int grid = (Btot + GROUPS - 1) / GROUPS;     // 4096 blocks x 256 thr
  ekf_kernel<<<grid, TPB, 0, stream>>>(mu_prev, Sigma, u, z, A, Bm, C, Q, R,
                                       mu_out, sig_out, Btot);
}